// Round 24
// baseline (515.102 us; speedup 1.0000x reference)
//
#include <hip/hip_runtime.h>
#include <hip/hip_bf16.h>

typedef unsigned short u16;
typedef short bf16x8 __attribute__((ext_vector_type(8)));
typedef unsigned short u16x8 __attribute__((ext_vector_type(8)));
typedef float f32x4 __attribute__((ext_vector_type(4)));
typedef float f32x16 __attribute__((ext_vector_type(16)));

#define NB 4
#define NS 2048
#define DM 256
#define NH 4
#define DHD 64
#define MR (NB*NS)      /* 8192 */
#define BHC (NB*NH)     /* 16 */
#define BH2 32
#define M2 (2*MR)
#define ACH 4
#define ACK (NS/ACH)    /* 512 keys per chunk */
#define HS ((size_t)BHC*NS*DHD)

__device__ __forceinline__ u16 f2b(float f){
    __hip_bfloat16 h = __float2bfloat16(f);
    return __builtin_bit_cast(u16, h);
}
__device__ __forceinline__ float b2f(u16 u){
    unsigned v = ((unsigned)u) << 16; float f; __builtin_memcpy(&f, &v, 4); return f;
}
__device__ __forceinline__ float fexp2(float x){
    float r; asm("v_exp_f32 %0, %1" : "=v"(r) : "v"(x)); return r;
}
__device__ __forceinline__ unsigned cvt_pk(float lo, float hi){
    unsigned r; asm("v_cvt_pk_bf16_f32 %0, %1, %2" : "=v"(r) : "v"(lo), "v"(hi)); return r;
}
// swaps a.hi(lanes32-63) with b.lo(lanes0-31): a' = [a.lo|b.lo], b' = [a.hi|b.hi]
__device__ __forceinline__ void pl32swap(unsigned &a, unsigned &b){
    asm("v_permlane32_swap_b32 %0, %1" : "+v"(a), "+v"(b));
}

#define MFMA16(a,b,c) __builtin_amdgcn_mfma_f32_16x16x32_bf16((a),(b),(c),0,0,0)
#define MFMA32(a,b,c) __builtin_amdgcn_mfma_f32_32x32x16_bf16((a),(b),(c),0,0,0)

// ---------------- casts ----------------
__global__ void k_cast_desc(const float* __restrict__ d0, const float* __restrict__ d1, u16* __restrict__ dst){
    int i = (blockIdx.x*256 + threadIdx.x)*4;
    if (i + 3 >= 2*MR*DM) return;
    const float* src = (i < MR*DM) ? d0 : d1;
    int j = (i < MR*DM) ? i : i - MR*DM;
    float4 v = *(const float4*)(src + j);
    dst[i+0] = f2b(v.x); dst[i+1] = f2b(v.y); dst[i+2] = f2b(v.z); dst[i+3] = f2b(v.w);
}
__device__ __forceinline__ void wt_one(const float* W, u16* Wt, int idx, int K, int Nc){
    int k = idx % K, nc = idx / K;
    Wt[idx] = f2b(W[(size_t)k*Nc + nc]);
}
__global__ void k_cwt1(const float* __restrict__ W, u16* __restrict__ Wt, int K, int Nc){
    int idx = blockIdx.x*256 + threadIdx.x;
    if (idx < K*Nc) wt_one(W, Wt, idx, K, Nc);
}
__global__ void k_cwt4(const float* W0, const float* W1, const float* W2, const float* W3,
                       u16* T0, u16* T1, u16* T2, u16* T3){
    int idx = blockIdx.x*256 + threadIdx.x;
    int w = idx >> 16, j = idx & 65535;
    const float* W = (w==0)?W0:(w==1)?W1:(w==2)?W2:W3;
    u16* T = (w==0)?T0:(w==1)?T1:(w==2)?T2:T3;
    wt_one(W, T, j, 256, 256);
}
__global__ void k_cwt2a(const float* W0, const float* W1, u16* T0, u16* T1){
    int idx = blockIdx.x*256 + threadIdx.x;
    int w = idx >> 18, j = idx & 262143;
    wt_one(w? W1:W0, w? T1:T0, j, 512, 512);
}
__global__ void k_cwt2b(const float* W0, const float* W1, u16* T0, u16* T1){
    int idx = blockIdx.x*256 + threadIdx.x;
    int w = idx >> 17, j = idx & 131071;
    wt_one(w? W1:W0, w? T1:T0, j, 512, 256);
}
__global__ void k_fill_x(const u16* __restrict__ Xb, u16* __restrict__ cat){
    int i = blockIdx.x*256 + threadIdx.x;
    if (i >= M2*DM/8) return;
    int row = i >> 5, c8 = i & 31;
    *(u16x8*)(cat + (size_t)row*512 + c8*8) = *(const u16x8*)(Xb + (size_t)row*256 + c8*8);
}

// ---------------- shared GEMM core (verified) ----------------
#define GEMM_CORE(Aptr, Wptr, Kdim) \
    __shared__ __attribute__((aligned(16))) u16 As[64*72]; \
    __shared__ __attribute__((aligned(16))) u16 Bs[64*72]; \
    const int tid = threadIdx.x; \
    const int lane = tid & 63, widx = tid >> 6; \
    const int wr = widx >> 1, wc = widx & 1; \
    const int r16 = lane & 15, g = lane >> 4; \
    const int m0 = blockIdx.x * 64, n0 = blockIdx.y * 64; \
    f32x4 acc[2][2] = {}; \
    { const int nkt = (Kdim) >> 6; \
    for (int kt = 0; kt < nkt; ++kt){ \
        _Pragma("unroll") \
        for (int it = 0; it < 2; ++it){ \
            int ch = tid + it*256; \
            int row = ch >> 3, cc = ch & 7; \
            *(u16x8*)(As + row*72 + cc*8) = *(const u16x8*)((Aptr) + (size_t)(m0+row)*(Kdim) + kt*64 + cc*8); \
            *(u16x8*)(Bs + row*72 + cc*8) = *(const u16x8*)((Wptr) + (size_t)(n0+row)*(Kdim) + kt*64 + cc*8); \
        } \
        __syncthreads(); \
        _Pragma("unroll") \
        for (int s = 0; s < 2; ++s){ \
            bf16x8 a0 = *(const bf16x8*)(As + (wr*32 +      r16)*72 + s*32 + g*8); \
            bf16x8 a1 = *(const bf16x8*)(As + (wr*32 + 16 + r16)*72 + s*32 + g*8); \
            bf16x8 b0 = *(const bf16x8*)(Bs + (wc*32 +      r16)*72 + s*32 + g*8); \
            bf16x8 b1 = *(const bf16x8*)(Bs + (wc*32 + 16 + r16)*72 + s*32 + g*8); \
            acc[0][0] = MFMA16(a0, b0, acc[0][0]); \
            acc[0][1] = MFMA16(a0, b1, acc[0][1]); \
            acc[1][0] = MFMA16(a1, b0, acc[1][0]); \
            acc[1][1] = MFMA16(a1, b1, acc[1][1]); \
        } \
        __syncthreads(); \
    } }

__global__ __launch_bounds__(256) void k_gemm(const u16* __restrict__ A, const u16* __restrict__ Wt,
                                              const float* __restrict__ bias, float* __restrict__ C,
                                              int K, int Nc){
    GEMM_CORE(A, Wt, K)
#pragma unroll
    for (int mi = 0; mi < 2; ++mi)
#pragma unroll
    for (int ni = 0; ni < 2; ++ni){
        int row = m0 + wr*32 + mi*16 + g*4;
        int col = n0 + wc*32 + ni*16 + r16;
        float bc = bias[col];
        float* cp = C + (size_t)row*Nc + col;
#pragma unroll
        for (int rr = 0; rr < 4; ++rr) cp[(size_t)rr*Nc] = acc[mi][ni][rr] + bc;
    }
}
__global__ __launch_bounds__(256) void k_gemm_cat(const u16* __restrict__ A, const u16* __restrict__ Wt,
                                                  const float* __restrict__ bias, u16* __restrict__ cat,
                                                  int K){
    GEMM_CORE(A, Wt, K)
#pragma unroll
    for (int mi = 0; mi < 2; ++mi)
#pragma unroll
    for (int ni = 0; ni < 2; ++ni){
        int row = m0 + wr*32 + mi*16 + g*4;
        int col = n0 + wc*32 + ni*16 + r16;
        float bc = bias[col];
        u16* cp = cat + (size_t)row*512 + 256 + col;
#pragma unroll
        for (int rr = 0; rr < 4; ++rr) cp[(size_t)rr*512] = f2b(acc[mi][ni][rr] + bc);
    }
}
__global__ __launch_bounds__(256) void k_gemm_qk(const u16* __restrict__ A, const u16* __restrict__ Wt,
                                                 const float* __restrict__ bias,
                                                 u16* __restrict__ dstQ, u16* __restrict__ dstK, int K){
    GEMM_CORE(A, Wt, K)
#pragma unroll
    for (int mi = 0; mi < 2; ++mi)
#pragma unroll
    for (int ni = 0; ni < 2; ++ni){
        int row = m0 + wr*32 + mi*16 + g*4;
        int col = n0 + wc*32 + ni*16 + r16;
        float bc = bias[col];
        int h = col >> 6, dh = col & 63;
#pragma unroll
        for (int rr = 0; rr < 4; ++rr){
            int r2 = row + rr;
            int b = r2 >> 11, n = r2 & (NS-1);
            u16 v = f2b(acc[mi][ni][rr] + bc);
            size_t off2 = ((size_t)(b*NH + h)*NS + n)*DHD + dh;
            dstQ[off2] = v;
            dstK[off2] = v;
        }
    }
}
__global__ __launch_bounds__(256) void k_gemm_vt(const u16* __restrict__ A, const u16* __restrict__ Wt,
                                                 const float* __restrict__ bias, u16* __restrict__ VT, int K){
    GEMM_CORE(A, Wt, K)
#pragma unroll
    for (int mi = 0; mi < 2; ++mi)
#pragma unroll
    for (int ni = 0; ni < 2; ++ni){
        int row = m0 + wr*32 + mi*16 + g*4;
        int col = n0 + wc*32 + ni*16 + r16;
        float bc = bias[col];
        int h = col >> 6, dh = col & 63;
#pragma unroll
        for (int rr = 0; rr < 4; ++rr){
            int r2 = row + rr;
            int b = r2 >> 11, n = r2 & (NS-1);
            VT[((size_t)(b*NH + h)*DHD + dh)*NS + n] = f2b(acc[mi][ni][rr] + bc);
        }
    }
}
__global__ __launch_bounds__(256) void k_gemm_resid_mid(const u16* __restrict__ A, const u16* __restrict__ Wt,
                                                        const float* __restrict__ bias,
                                                        const float* __restrict__ X0, const float* __restrict__ X1,
                                                        u16* __restrict__ OutB, int K){
    GEMM_CORE(A, Wt, K)
#pragma unroll
    for (int mi = 0; mi < 2; ++mi)
#pragma unroll
    for (int ni = 0; ni < 2; ++ni){
        int row = m0 + wr*32 + mi*16 + g*4;
        int col = n0 + wc*32 + ni*16 + r16;
        float bc = bias[col];
#pragma unroll
        for (int rr = 0; rr < 4; ++rr){
            int r2 = row + rr;
            const float* X = (r2 < MR) ? X0 : X1;
            size_t xi = (size_t)(r2 < MR ? r2 : r2 - MR)*DM + col;
            OutB[(size_t)r2*DM + col] = f2b(acc[mi][ni][rr] + bc + X[xi]);
        }
    }
}
__global__ __launch_bounds__(256) void k_gemm_resid_out(const u16* __restrict__ A, const u16* __restrict__ Wt,
                                                        const float* __restrict__ bias,
                                                        const u16* __restrict__ Xb, float* __restrict__ OutF, int K){
    GEMM_CORE(A, Wt, K)
#pragma unroll
    for (int mi = 0; mi < 2; ++mi)
#pragma unroll
    for (int ni = 0; ni < 2; ++ni){
        int row = m0 + wr*32 + mi*16 + g*4;
        int col = n0 + wc*32 + ni*16 + r16;
        float bc = bias[col];
#pragma unroll
        for (int rr = 0; rr < 4; ++rr){
            size_t idx = (size_t)(row+rr)*DM + col;
            OutF[idx] = acc[mi][ni][rr] + bc + b2f(Xb[idx]);
        }
    }
}

// ---------------- qkv epilogue ----------------
__global__ void k_qkv_epi(const float* __restrict__ C, const float* __restrict__ kp,
                          u16* __restrict__ Q, u16* __restrict__ K, u16* __restrict__ VT){
    int idx = blockIdx.x*blockDim.x + threadIdx.x;
    if (idx >= BHC*NS*32) return;
    int dhp = idx & 31;
    int n   = (idx >> 5) & (NS-1);
    int bh  = idx >> 16;
    int b = bh >> 2, h = bh & 3;
    size_t crow = (size_t)(b*NS + n)*768 + h*192 + dhp*6;
    float q0 = C[crow+0], k0 = C[crow+1], v0 = C[crow+2];
    float q1 = C[crow+3], k1 = C[crow+4], v1 = C[crow+5];
    size_t kb = (size_t)b*(NS*DHD) + (size_t)n*DHD + dhp*2;
    float c0 = kp[kb], c1 = kp[kb+1];
    float s0 = kp[kb + (size_t)NB*NS*DHD], s1 = kp[kb + (size_t)NB*NS*DHD + 1];
    float qr0 = q0*c0 - q1*s0, qr1 = q1*c1 + q0*s1;
    float kr0 = k0*c0 - k1*s0, kr1 = k1*c1 + k0*s1;
    size_t qk = ((size_t)bh*NS + n)*DHD + dhp*2;
    Q[qk]   = f2b(qr0); Q[qk+1] = f2b(qr1);
    K[qk]   = f2b(kr0); K[qk+1] = f2b(kr1);
    size_t vt = ((size_t)bh*DHD + dhp*2)*NS + n;
    VT[vt]      = f2b(v0);
    VT[vt + NS] = f2b(v1);
}

// ---------------- attention v5: 2-tile pipeline, cvt_pk + permlane32_swap, setprio ----------------
__global__ __launch_bounds__(256) void k_attn3(const u16* __restrict__ Q, const u16* __restrict__ Kb,
                                               const u16* __restrict__ VT,
                                               u16* __restrict__ opart, float* __restrict__ mpart,
                                               float* __restrict__ lpart, float scale_l2e){
    const int tid = threadIdx.x, lane = tid & 63, widx = tid >> 6;
    const int l31 = lane & 31, hi = lane >> 5;
    const int gw = blockIdx.x*4 + widx;
    const int bh = gw >> 6, qt = gw & 63;
    const int q0 = qt * 32;
    const int ck = blockIdx.y;

    bf16x8 qf[4];
    {
        const u16* Qp = Q + ((size_t)bh*NS + q0 + l31)*DHD + hi*8;
#pragma unroll
        for (int kk = 0; kk < 4; ++kk){
            u16x8 raw = *(const u16x8*)(Qp + kk*16);
            u16x8 sc;
#pragma unroll
            for (int i = 0; i < 8; ++i) sc[i] = f2b(b2f(raw[i]) * scale_l2e);
            qf[kk] = __builtin_bit_cast(bf16x8, sc);
        }
    }

    f32x16 o0 = {}, o1 = {};
    float m_run = -1e30f, l_run = 0.f;
    const u16* Kbase = Kb + ((size_t)bh*NS + ck*ACK)*DHD;
    const u16* Vb0 = VT + ((size_t)bh*DHD +      l31)*NS + ck*ACK;
    const u16* Vb1 = VT + ((size_t)bh*DHD + 32 + l31)*NS + ck*ACK;

    for (int jt = 0; jt < ACK/64; ++jt){
        const u16* KpA = Kbase + (size_t)(jt*64 + l31)*DHD + hi*8;
        const u16* KpB = KpA + (size_t)32*DHD;
        f32x16 sA = {}, sB = {};
        __builtin_amdgcn_s_setprio(1);
#pragma unroll
        for (int kk = 0; kk < 4; ++kk){
            bf16x8 kf = *(const bf16x8*)(KpA + kk*16);
            sA = MFMA32(kf, qf[kk], sA);
        }
#pragma unroll
        for (int kk = 0; kk < 4; ++kk){
            bf16x8 kf = *(const bf16x8*)(KpB + kk*16);
            sB = MFMA32(kf, qf[kk], sB);
        }
        __builtin_amdgcn_s_setprio(0);
        // combined max tree over 32 scores
        float t[16];
#pragma unroll
        for (int i = 0; i < 16; ++i) t[i] = fmaxf(sA[i], sB[i]);
#pragma unroll
        for (int i = 0; i < 8; ++i) t[i] = fmaxf(t[i], t[i+8]);
#pragma unroll
        for (int i = 0; i < 4; ++i) t[i] = fmaxf(t[i], t[i+4]);
        float mx = fmaxf(fmaxf(t[0],t[1]), fmaxf(t[2],t[3]));
        mx = fmaxf(mx, __shfl_xor(mx, 32));
        if (__any(mx > m_run + 8.0f)){
            float mn = fmaxf(m_run, mx);
            float corr = fexp2(m_run - mn);
            l_run *= corr;
            o0 *= corr; o1 *= corr;
            m_run = mn;
        }
        float pA[16], pB[16];
#pragma unroll
        for (int i = 0; i < 16; ++i) pA[i] = fexp2(sA[i] - m_run);
#pragma unroll
        for (int i = 0; i < 16; ++i) pB[i] = fexp2(sB[i] - m_run);
        float u[16];
#pragma unroll
        for (int i = 0; i < 16; ++i) u[i] = pA[i] + pB[i];
#pragma unroll
        for (int i = 0; i < 8; ++i) u[i] = u[i] + u[i+8];
#pragma unroll
        for (int i = 0; i < 4; ++i) u[i] = u[i] + u[i+4];
        float sum = (u[0]+u[1]) + (u[2]+u[3]);
        sum += __shfl_xor(sum, 32);
        l_run += sum;
        // pack via cvt_pk + permlane32_swap
        unsigned cA[8], cB[8];
#pragma unroll
        for (int i = 0; i < 8; ++i) cA[i] = cvt_pk(pA[2*i], pA[2*i+1]);
#pragma unroll
        for (int i = 0; i < 8; ++i) cB[i] = cvt_pk(pB[2*i], pB[2*i+1]);
        pl32swap(cA[0], cA[2]); pl32swap(cA[1], cA[3]);
        pl32swap(cA[4], cA[6]); pl32swap(cA[5], cA[7]);
        pl32swap(cB[0], cB[2]); pl32swap(cB[1], cB[3]);
        pl32swap(cB[4], cB[6]); pl32swap(cB[5], cB[7]);
        bf16x8 pbA0, pbA1, pbB0, pbB1;
        { unsigned w[4] = {cA[0], cA[1], cA[2], cA[3]}; __builtin_memcpy(&pbA0, w, 16); }
        { unsigned w[4] = {cA[4], cA[5], cA[6], cA[7]}; __builtin_memcpy(&pbA1, w, 16); }
        { unsigned w[4] = {cB[0], cB[1], cB[2], cB[3]}; __builtin_memcpy(&pbB0, w, 16); }
        { unsigned w[4] = {cB[4], cB[5], cB[6], cB[7]}; __builtin_memcpy(&pbB1, w, 16); }
        // PV: 8 MFMAs in one cluster
        bf16x8 vA00 = *(const bf16x8*)(Vb0 + jt*64 +      hi*8);
        bf16x8 vA01 = *(const bf16x8*)(Vb0 + jt*64 + 16 + hi*8);
        bf16x8 vB00 = *(const bf16x8*)(Vb0 + jt*64 + 32 + hi*8);
        bf16x8 vB01 = *(const bf16x8*)(Vb0 + jt*64 + 48 + hi*8);
        bf16x8 vA10 = *(const bf16x8*)(Vb1 + jt*64 +      hi*8);
        bf16x8 vA11 = *(const bf16x8*)(Vb1 + jt*64 + 16 + hi*8);
        bf16x8 vB10 = *(const bf16x8*)(Vb1 + jt*64 + 32 + hi*8);
        bf16x8 vB11 = *(const bf16x8*)(Vb1 + jt*64 + 48 + hi*8);
        __builtin_amdgcn_s_setprio(1);
        o0 = MFMA32(vA00, pbA0, o0);
        o1 = MFMA32(vA10, pbA0, o1);
        o0 = MFMA32(vA01, pbA1, o0);
        o1 = MFMA32(vA11, pbA1, o1);
        o0 = MFMA32(vB00, pbB0, o0);
        o1 = MFMA32(vB10, pbB0, o1);
        o0 = MFMA32(vB01, pbB1, o0);
        o1 = MFMA32(vB11, pbB1, o1);
        __builtin_amdgcn_s_setprio(0);
    }
    const size_t rq = ((size_t)ck*BH2 + bh)*NS + q0 + l31;
    if (!hi){ mpart[rq] = m_run; lpart[rq] = l_run; }
    unsigned* op32 = (unsigned*)(opart + rq*64);
#pragma unroll
    for (int r = 0; r < 16; r += 2){
        int d = (r & 3) + 8*(r >> 2) + 4*hi;       // even
        op32[d >> 1]        = cvt_pk(o0[r], o0[r+1]);
        op32[(d >> 1) + 16] = cvt_pk(o1[r], o1[r+1]);
    }
}

// combine ACH chunks -> ctx2 bf16
__global__ __launch_bounds__(256) void k_attn_comb(const u16* __restrict__ opart,
                                                   const float* __restrict__ mpart,
                                                   const float* __restrict__ lpart,
                                                   u16* __restrict__ ctx){
    int idx = blockIdx.x*256 + threadIdx.x;
    if (idx >= BH2*NS*64) return;
    int d = idx & 63; int n = (idx >> 6) & (NS-1); int bh2 = idx >> 17;
    size_t row = (size_t)bh2*NS + n;
    const size_t CH = (size_t)BH2*NS;
    float M = -1e30f;
#pragma unroll
    for (int ck = 0; ck < ACH; ++ck) M = fmaxf(M, mpart[ck*CH + row]);
    float l = 0.f, o = 0.f;
#pragma unroll
    for (int ck = 0; ck < ACH; ++ck){
        float e = fexp2(mpart[ck*CH + row] - M);
        l += lpart[ck*CH + row] * e;
        o += b2f(opart[(ck*CH + row)*64 + d]) * e;
    }
    int side = bh2 >> 4, bh = bh2 & 15;
    int b = bh >> 2, h = bh & 3;
    ctx[((size_t)side*MR + (size_t)b*NS + n)*DM + h*DHD + d] = f2b(o / l);
}

// ---------------- LN + GELU ----------------
__global__ __launch_bounds__(256) void k_ln_gelu(const float* __restrict__ C, const float* __restrict__ gam,
                                                 const float* __restrict__ bet, u16* __restrict__ hb){
    int row = blockIdx.x, t = threadIdx.x;
    const float* cr = C + (size_t)row*512;
    float x0 = cr[t], x1 = cr[t+256];
    float s = x0 + x1, q = x0*x0 + x1*x1;
#pragma unroll
    for (int offs = 1; offs < 64; offs <<= 1){
        s += __shfl_xor(s, offs);
        q += __shfl_xor(q, offs);
    }
    __shared__ float ss[4], qq[4];
    int w = t >> 6, ln = t & 63;
    if (ln == 0){ ss[w] = s; qq[w] = q; }
    __syncthreads();
    s = ss[0]+ss[1]+ss[2]+ss[3];
    q = qq[0]+qq[1]+qq[2]+qq[3];
    float mu = s * (1.f/512.f);
    float var = q * (1.f/512.f) - mu*mu;
    float rs = rsqrtf(var + 1e-5f);
    float y0 = (x0 - mu)*rs*gam[t]     + bet[t];
    float y1 = (x1 - mu)*rs*gam[t+256] + bet[t+256];
    float g0 = 0.5f*y0*(1.f + erff(y0*0.70710678118654752f));
    float g1 = 0.5f*y1*(1.f + erff(y1*0.70710678118654752f));
    hb[(size_t)row*512 + t]       = f2b(g0);
    hb[(size_t)row*512 + 256 + t] = f2b(g1);
}

// ---------------- host ----------------
extern "C" void kernel_launch(void* const* d_in, const int* in_sizes, int n_in,
                              void* d_out, int out_size, void* d_ws, size_t ws_size,
                              hipStream_t stream)
{
    const float* kp0   = (const float*)d_in[0];
    const float* kp1   = (const float*)d_in[1];
    const float* desc0 = (const float*)d_in[2];
    const float* desc1 = (const float*)d_in[3];
    const float* saWqkv= (const float*)d_in[4];
    const float* sabqkv= (const float*)d_in[5];
    const float* saWo  = (const float*)d_in[6];
    const float* sabo  = (const float*)d_in[7];
    const float* saW1  = (const float*)d_in[8];
    const float* sab1  = (const float*)d_in[9];
    const float* sag   = (const float*)d_in[10];
    const float* sabe  = (const float*)d_in[11];
    const float* saW2  = (const float*)d_in[12];
    const float* sab2  = (const float*)d_in[13];
    const float* caWqk = (const float*)d_in[14];
    const float* cabqk = (const float*)d_in[15];
    const float* caWv  = (const float*)d_in[16];
    const float* cabv  = (const float*)d_in[17];
    const float* caWo  = (const float*)d_in[18];
    const float* cabo  = (const float*)d_in[19];
    const float* caW1  = (const float*)d_in[20];
    const float* cab1  = (const float*)d_in[21];
    const float* cag   = (const float*)d_in[22];
    const float* cabe  = (const float*)d_in[23];
    const float* caW2  = (const float*)d_in[24];
    const float* cab2  = (const float*)d_in[25];

    char* ws = (char*)d_ws;
    size_t off = 0;
    auto alloc = [&](size_t b)->char*{ char* p = ws + off; off = (off + b + 255) & ~(size_t)255; return p; };

    u16* wqkvT = (u16*)alloc(768*256*2);
    u16* woST  = (u16*)alloc(256*256*2);
    u16* w1ST  = (u16*)alloc(512*512*2);
    u16* w2ST  = (u16*)alloc(256*512*2);
    u16* wqkT  = (u16*)alloc(256*256*2);
    u16* wvT   = (u16*)alloc(256*256*2);
    u16* woCT  = (u16*)alloc(256*256*2);
    u16* w1CT  = (u16*)alloc(512*512*2);
    u16* w2CT  = (u16*)alloc(256*512*2);
    u16* X01b  = (u16*)alloc((size_t)M2*DM*2);
    u16* Q2    = (u16*)alloc((size_t)BH2*NS*DHD*2);
    u16* K2    = (u16*)alloc((size_t)BH2*NS*DHD*2);
    u16* V2    = (u16*)alloc((size_t)BH2*NS*DHD*2);
    u16* ctx2  = (u16*)alloc((size_t)M2*DM*2);
    u16* midb2 = (u16*)alloc((size_t)M2*DM*2);
    u16* cat2  = (u16*)alloc((size_t)M2*512*2);
    u16* hb2   = cat2;
    char* uni  = alloc(33554432);
    float* Cbuf = (float*)uni;
    u16*  opart = (u16*)uni;
    float* mpart = (float*)alloc((size_t)ACH*BH2*NS*4);
    float* lpart = (float*)alloc((size_t)ACH*BH2*NS*4);

    k_cwt1 <<<768, 256, 0, stream>>>(saWqkv, wqkvT, 256, 768);
    k_cwt4 <<<1024,256, 0, stream>>>(saWo, caWqk, caWv, caWo, woST, wqkT, wvT, woCT);
    k_cwt2a<<<2048,256, 0, stream>>>(saW1, caW1, w1ST, w1CT);
    k_cwt2b<<<1024,256, 0, stream>>>(saW2, caW2, w2ST, w2CT);
    k_cast_desc<<<4096,256,0,stream>>>(desc0, desc1, X01b);

    const dim3 AG(512, ACH);
    const float SC = 0.125f * 1.44269504088896f;

    // ================= self blocks (batched) =================
    k_gemm<<<dim3(128,12),256,0,stream>>>(X01b,            wqkvT, sabqkv, Cbuf, 256, 768);
    k_qkv_epi<<<4096,256,0,stream>>>(Cbuf, kp0, Q2, K2, V2);
    k_gemm<<<dim3(128,12),256,0,stream>>>(X01b + (size_t)MR*DM, wqkvT, sabqkv, Cbuf, 256, 768);
    k_qkv_epi<<<4096,256,0,stream>>>(Cbuf, kp1, Q2 + HS, K2 + HS, V2 + HS);
    k_attn3<<<AG,256,0,stream>>>(Q2, K2, V2, opart, mpart, lpart, SC);
    k_attn_comb<<<16384,256,0,stream>>>(opart, mpart, lpart, ctx2);
    k_fill_x<<<2048,256,0,stream>>>(X01b, cat2);
    k_gemm_cat<<<dim3(256,4),256,0,stream>>>(ctx2, woST, sabo, cat2, 256);
    k_gemm<<<dim3(256,8),256,0,stream>>>(cat2, w1ST, sab1, Cbuf, 512, 512);
    k_ln_gelu<<<16384,256,0,stream>>>(Cbuf, sag, sabe, hb2);
    k_gemm_resid_mid<<<dim3(256,4),256,0,stream>>>(hb2, w2ST, sab2, desc0, desc1, midb2, 512);

    // ================= cross projections =================
    k_gemm_qk<<<dim3(128,4),256,0,stream>>>(midb2,                 wqkT, cabqk, Q2,      K2 + HS, 256);
    k_gemm_qk<<<dim3(128,4),256,0,stream>>>(midb2 + (size_t)MR*DM, wqkT, cabqk, Q2 + HS, K2,      256);
    k_gemm_vt<<<dim3(128,4),256,0,stream>>>(midb2 + (size_t)MR*DM, wvT,  cabv,  V2,      256);
    k_gemm_vt<<<dim3(128,4),256,0,stream>>>(midb2,                 wvT,  cabv,  V2 + HS, 256);

    // ================= cross blocks (batched) =================
    k_attn3<<<AG,256,0,stream>>>(Q2, K2, V2, opart, mpart, lpart, SC);
    k_attn_comb<<<16384,256,0,stream>>>(opart, mpart, lpart, ctx2);
    k_fill_x<<<2048,256,0,stream>>>(midb2, cat2);
    k_gemm_cat<<<dim3(256,4),256,0,stream>>>(ctx2, woCT, cabo, cat2, 256);
    k_gemm<<<dim3(256,8),256,0,stream>>>(cat2, w1CT, cab1, Cbuf, 512, 512);
    k_ln_gelu<<<16384,256,0,stream>>>(Cbuf, cag, cabe, hb2);
    k_gemm_resid_out<<<dim3(256,4),256,0,stream>>>(hb2, w2CT, cab2, midb2, (float*)d_out, 512);

    (void)in_sizes; (void)n_in; (void)out_size; (void)ws_size;
}